// Round 1
// baseline (383.053 us; speedup 1.0000x reference)
//
#include <hip/hip_runtime.h>
#include <math.h>

#define NROWS 4194304
#define NCLS  10

// Each thread handles 2 rows (20 floats = 5 aligned float4 loads).
// Row layout: f0=[x0..x3] f1=[x4..x7] f2=[x8,x9,y0,y1] f3=[y2..y5] f4=[y6..y9]

__device__ __forceinline__ void row_stats(const float r[NCLS], int t,
                                          float* nll, bool* amax_is_3) {
    float m = r[0];
    int am = 0;
#pragma unroll
    for (int j = 1; j < NCLS; ++j) {
        bool g = r[j] > m;          // strict > keeps FIRST max (jnp.argmax semantics)
        m  = g ? r[j] : m;
        am = g ? j    : am;
    }
    float s  = 0.0f;
    float xt = r[0];
#pragma unroll
    for (int j = 0; j < NCLS; ++j) {
        s += __expf(r[j] - m);
        if (j == t) xt = r[j];      // unrolled -> v_cndmask chain
    }
    *nll = m + __logf(s) - xt;
    *amax_is_3 = (am == 3);
}

__global__ __launch_bounds__(256) void ce_partial_kernel(
        const float4* __restrict__ x4,       // logits viewed as float4[B*C/4]
        const int2*   __restrict__ tgt2,     // targets viewed as int2[B/2]
        float* __restrict__ ws_sum,
        int*   __restrict__ ws_flag) {
    const size_t tid = (size_t)blockIdx.x * blockDim.x + threadIdx.x; // rows 2t,2t+1
    const float4 f0 = x4[5 * tid + 0];
    const float4 f1 = x4[5 * tid + 1];
    const float4 f2 = x4[5 * tid + 2];
    const float4 f3 = x4[5 * tid + 3];
    const float4 f4 = x4[5 * tid + 4];
    const int2 t = tgt2[tid];

    const float r0[NCLS] = {f0.x, f0.y, f0.z, f0.w, f1.x, f1.y, f1.z, f1.w, f2.x, f2.y};
    const float r1[NCLS] = {f2.z, f2.w, f3.x, f3.y, f3.z, f3.w, f4.x, f4.y, f4.z, f4.w};

    float nll0, nll1;
    bool a3_0, a3_1;
    row_stats(r0, t.x, &nll0, &a3_0);
    row_stats(r1, t.y, &nll1, &a3_1);

    float sum = nll0 + nll1;
    bool flag = (t.x == 2 && a3_0) || (t.y == 2 && a3_1);

    // wave (64-lane) reduction
#pragma unroll
    for (int off = 32; off > 0; off >>= 1) sum += __shfl_down(sum, off);
    const bool wany = __any(flag);

    __shared__ float wsum[4];   // 256 threads = 4 waves
    __shared__ int   sflag;
    const int lane = threadIdx.x & 63;
    const int wid  = threadIdx.x >> 6;
    if (threadIdx.x == 0) sflag = 0;
    __syncthreads();
    if (lane == 0) {
        wsum[wid] = sum;
        if (wany) atomicOr(&sflag, 1);
    }
    __syncthreads();
    if (threadIdx.x == 0) {
        const float bs = wsum[0] + wsum[1] + wsum[2] + wsum[3];
        atomicAdd(ws_sum, bs);                 // device-scope by default
        if (sflag) atomicOr(ws_flag, 1);
    }
}

__global__ void finalize_kernel(const float* __restrict__ ws_sum,
                                const int*   __restrict__ ws_flag,
                                const int*   __restrict__ epoch,
                                float* __restrict__ out) {
    const float corr = 64.0f * __powf((float)epoch[0], -0.65f) + 0.01f;
    out[0] = ws_sum[0] * (1.0f / (float)NROWS) + (ws_flag[0] ? corr : 0.0f);
}

extern "C" void kernel_launch(void* const* d_in, const int* in_sizes, int n_in,
                              void* d_out, int out_size, void* d_ws, size_t ws_size,
                              hipStream_t stream) {
    const float4* x4   = (const float4*)d_in[0];  // output: fp32 [B,10]
    const int2*   tgt2 = (const int2*)  d_in[1];  // target: int32 [B]
    const int*    ep   = (const int*)   d_in[2];  // epoch scalar
    float* out = (float*)d_out;

    float* ws_sum  = (float*)d_ws;
    int*   ws_flag = (int*)d_ws + 1;

    // ws is poisoned 0xAA before every timed launch -> zero accumulator + flag
    hipMemsetAsync(d_ws, 0, 2 * sizeof(float), stream);

    const int threads = 256;
    const int blocks  = (NROWS / 2) / threads;  // 8192, exact
    ce_partial_kernel<<<blocks, threads, 0, stream>>>(x4, tgt2, ws_sum, ws_flag);
    finalize_kernel<<<1, 1, 0, stream>>>(ws_sum, ws_flag, ep, out);
}

// Round 2
// 249.647 us; speedup vs baseline: 1.5344x; 1.5344x over previous
//
#include <hip/hip_runtime.h>
#include <math.h>

#define NROWS  4194304
#define NBLK   8192          // (NROWS/2) / 256 threads, exact
#define INV_B  (1.0f / 4194304.0f)

// All-scalar row computation: forces register allocation (R0's array version
// spilled to scratch -> VGPR_Count=16, 207us latency-bound).
__device__ __forceinline__ void row10(float a0, float a1, float a2, float a3,
                                      float a4, float a5, float a6, float a7,
                                      float a8, float a9, int t,
                                      float& nll, bool& amax_is_3) {
    float m = a0;
    int am = 0;
#define AMAX_STEP(j, aj) { bool g = (aj) > m; m = g ? (aj) : m; am = g ? (j) : am; }
    AMAX_STEP(1, a1) AMAX_STEP(2, a2) AMAX_STEP(3, a3) AMAX_STEP(4, a4)
    AMAX_STEP(5, a5) AMAX_STEP(6, a6) AMAX_STEP(7, a7) AMAX_STEP(8, a8)
    AMAX_STEP(9, a9)
#undef AMAX_STEP
    float s = __expf(a0 - m);
    s += __expf(a1 - m);  s += __expf(a2 - m);  s += __expf(a3 - m);
    s += __expf(a4 - m);  s += __expf(a5 - m);  s += __expf(a6 - m);
    s += __expf(a7 - m);  s += __expf(a8 - m);  s += __expf(a9 - m);
    float xt = a0;
    xt = (t == 1) ? a1 : xt;  xt = (t == 2) ? a2 : xt;  xt = (t == 3) ? a3 : xt;
    xt = (t == 4) ? a4 : xt;  xt = (t == 5) ? a5 : xt;  xt = (t == 6) ? a6 : xt;
    xt = (t == 7) ? a7 : xt;  xt = (t == 8) ? a8 : xt;  xt = (t == 9) ? a9 : xt;
    nll = m + __logf(s) - xt;
    amax_is_3 = (am == 3);
}

// Each thread: 2 rows = 20 floats = 5 aligned float4 loads (rows are 40B).
// f0=[x0..x3] f1=[x4..x7] f2=[x8,x9,y0,y1] f3=[y2..y5] f4=[y6..y9]
__global__ __launch_bounds__(256) void ce_partial_kernel(
        const float4* __restrict__ x4,
        const int2*   __restrict__ tgt2,
        float* __restrict__ partial,     // [NBLK]
        int*   __restrict__ flags) {     // [NBLK]
    const size_t tid = (size_t)blockIdx.x * blockDim.x + threadIdx.x;
    const float4 f0 = x4[5 * tid + 0];
    const float4 f1 = x4[5 * tid + 1];
    const float4 f2 = x4[5 * tid + 2];
    const float4 f3 = x4[5 * tid + 3];
    const float4 f4 = x4[5 * tid + 4];
    const int2 t = tgt2[tid];

    float nll0, nll1;
    bool a3_0, a3_1;
    row10(f0.x, f0.y, f0.z, f0.w, f1.x, f1.y, f1.z, f1.w, f2.x, f2.y, t.x, nll0, a3_0);
    row10(f2.z, f2.w, f3.x, f3.y, f3.z, f3.w, f4.x, f4.y, f4.z, f4.w, t.y, nll1, a3_1);

    float sum = nll0 + nll1;
    int flag = ((t.x == 2) & a3_0) | ((t.y == 2) & a3_1);

    // 64-lane wave reduction
#pragma unroll
    for (int off = 32; off > 0; off >>= 1) sum += __shfl_down(sum, off);
    flag = __any(flag) ? 1 : 0;

    __shared__ float wsum[4];    // 256 threads = 4 waves
    __shared__ int   wflag[4];
    const int lane = threadIdx.x & 63;
    const int wid  = threadIdx.x >> 6;
    if (lane == 0) { wsum[wid] = sum; wflag[wid] = flag; }
    __syncthreads();
    if (threadIdx.x == 0) {
        partial[blockIdx.x] = wsum[0] + wsum[1] + wsum[2] + wsum[3];
        flags[blockIdx.x]   = wflag[0] | wflag[1] | wflag[2] | wflag[3];
    }
}

__global__ __launch_bounds__(256) void reduce_kernel(
        const float* __restrict__ partial,
        const int*   __restrict__ flags,
        const int*   __restrict__ epoch,
        float* __restrict__ out) {
    float s = 0.0f;
    int f = 0;
    for (int i = threadIdx.x; i < NBLK; i += 256) {
        s += partial[i];
        f |= flags[i];
    }
#pragma unroll
    for (int off = 32; off > 0; off >>= 1) {
        s += __shfl_down(s, off);
        f |= __shfl_down(f, off);
    }
    __shared__ float wsum[4];
    __shared__ int   wflag[4];
    const int lane = threadIdx.x & 63;
    const int wid  = threadIdx.x >> 6;
    if (lane == 0) { wsum[wid] = s; wflag[wid] = f; }
    __syncthreads();
    if (threadIdx.x == 0) {
        const float tot = wsum[0] + wsum[1] + wsum[2] + wsum[3];
        const int ff    = wflag[0] | wflag[1] | wflag[2] | wflag[3];
        const float corr = 64.0f * __powf((float)epoch[0], -0.65f) + 0.01f;
        out[0] = tot * INV_B + (ff ? corr : 0.0f);
    }
}

extern "C" void kernel_launch(void* const* d_in, const int* in_sizes, int n_in,
                              void* d_out, int out_size, void* d_ws, size_t ws_size,
                              hipStream_t stream) {
    const float4* x4   = (const float4*)d_in[0];  // logits fp32 [B,10]
    const int2*   tgt2 = (const int2*)  d_in[1];  // targets int32 [B]
    const int*    ep   = (const int*)   d_in[2];  // epoch scalar
    float* out = (float*)d_out;

    float* partial = (float*)d_ws;            // NBLK floats
    int*   flags   = (int*)d_ws + NBLK;       // NBLK ints  (64 KB total)

    ce_partial_kernel<<<NBLK, 256, 0, stream>>>(x4, tgt2, partial, flags);
    reduce_kernel<<<1, 256, 0, stream>>>(partial, flags, ep, out);
}

// Round 3
// 246.569 us; speedup vs baseline: 1.5535x; 1.0125x over previous
//
#include <hip/hip_runtime.h>
#include <math.h>

#define NROWS  4194304
#define NBLK   8192          // (NROWS/2) / 256 threads, exact
#define INV_B  (1.0f / 4194304.0f)

// All-scalar row computation (R0's array version spilled to scratch).
__device__ __forceinline__ void row10(float a0, float a1, float a2, float a3,
                                      float a4, float a5, float a6, float a7,
                                      float a8, float a9, int t,
                                      float& nll, bool& amax_is_3) {
    float m = a0;
    int am = 0;
#define AMAX_STEP(j, aj) { bool g = (aj) > m; m = g ? (aj) : m; am = g ? (j) : am; }
    AMAX_STEP(1, a1) AMAX_STEP(2, a2) AMAX_STEP(3, a3) AMAX_STEP(4, a4)
    AMAX_STEP(5, a5) AMAX_STEP(6, a6) AMAX_STEP(7, a7) AMAX_STEP(8, a8)
    AMAX_STEP(9, a9)
#undef AMAX_STEP
    float s = __expf(a0 - m);
    s += __expf(a1 - m);  s += __expf(a2 - m);  s += __expf(a3 - m);
    s += __expf(a4 - m);  s += __expf(a5 - m);  s += __expf(a6 - m);
    s += __expf(a7 - m);  s += __expf(a8 - m);  s += __expf(a9 - m);
    float xt = a0;
    xt = (t == 1) ? a1 : xt;  xt = (t == 2) ? a2 : xt;  xt = (t == 3) ? a3 : xt;
    xt = (t == 4) ? a4 : xt;  xt = (t == 5) ? a5 : xt;  xt = (t == 6) ? a6 : xt;
    xt = (t == 7) ? a7 : xt;  xt = (t == 8) ? a8 : xt;  xt = (t == 9) ? a9 : xt;
    nll = m + __logf(s) - xt;
    amax_is_3 = (am == 3);
}

// Block tile: 512 rows = 1280 float4 = 20 KB.
// Phase 1: lane-contiguous coalesced global->LDS (16B/lane, ideal pattern).
// Phase 2: per-thread ds_read_b128 x5 at 80B stride.
//   b128 bank check (16-lane phases): group=(5t+k) mod 8, gcd(5,8)=1 ->
//   2 lanes/bank per phase = conflict-free (m136: 2-way is free).
__global__ __launch_bounds__(256) void ce_partial_kernel(
        const float4* __restrict__ x4,
        const int2*   __restrict__ tgt2,
        float* __restrict__ partial,     // [NBLK]
        int*   __restrict__ flags) {     // [NBLK]
    __shared__ float4 lds4[1280];

    const size_t base4 = (size_t)blockIdx.x * 1280;
#pragma unroll
    for (int k = 0; k < 5; ++k)
        lds4[k * 256 + threadIdx.x] = x4[base4 + k * 256 + threadIdx.x];

    const int2 t = tgt2[(size_t)blockIdx.x * 256 + threadIdx.x];
    __syncthreads();

    const float4* row = (const float4*)((const char*)lds4 + 80u * threadIdx.x);
    const float4 f0 = row[0];
    const float4 f1 = row[1];
    const float4 f2 = row[2];
    const float4 f3 = row[3];
    const float4 f4 = row[4];

    float nll0, nll1;
    bool a3_0, a3_1;
    row10(f0.x, f0.y, f0.z, f0.w, f1.x, f1.y, f1.z, f1.w, f2.x, f2.y, t.x, nll0, a3_0);
    row10(f2.z, f2.w, f3.x, f3.y, f3.z, f3.w, f4.x, f4.y, f4.z, f4.w, t.y, nll1, a3_1);

    float sum = nll0 + nll1;
    int flag = ((t.x == 2) & a3_0) | ((t.y == 2) & a3_1);

    // 64-lane wave reduction
#pragma unroll
    for (int off = 32; off > 0; off >>= 1) sum += __shfl_down(sum, off);
    flag = __any(flag) ? 1 : 0;

    __shared__ float wsum[4];    // 256 threads = 4 waves
    __shared__ int   wflag[4];
    const int lane = threadIdx.x & 63;
    const int wid  = threadIdx.x >> 6;
    if (lane == 0) { wsum[wid] = sum; wflag[wid] = flag; }
    __syncthreads();
    if (threadIdx.x == 0) {
        partial[blockIdx.x] = wsum[0] + wsum[1] + wsum[2] + wsum[3];
        flags[blockIdx.x]   = wflag[0] | wflag[1] | wflag[2] | wflag[3];
    }
}

__global__ __launch_bounds__(256) void reduce_kernel(
        const float* __restrict__ partial,
        const int*   __restrict__ flags,
        const int*   __restrict__ epoch,
        float* __restrict__ out) {
    float s = 0.0f;
    int f = 0;
    for (int i = threadIdx.x; i < NBLK; i += 256) {
        s += partial[i];
        f |= flags[i];
    }
#pragma unroll
    for (int off = 32; off > 0; off >>= 1) {
        s += __shfl_down(s, off);
        f |= __shfl_down(f, off);
    }
    __shared__ float wsum[4];
    __shared__ int   wflag[4];
    const int lane = threadIdx.x & 63;
    const int wid  = threadIdx.x >> 6;
    if (lane == 0) { wsum[wid] = s; wflag[wid] = f; }
    __syncthreads();
    if (threadIdx.x == 0) {
        const float tot = wsum[0] + wsum[1] + wsum[2] + wsum[3];
        const int ff    = wflag[0] | wflag[1] | wflag[2] | wflag[3];
        const float corr = 64.0f * __powf((float)epoch[0], -0.65f) + 0.01f;
        out[0] = tot * INV_B + (ff ? corr : 0.0f);
    }
}

extern "C" void kernel_launch(void* const* d_in, const int* in_sizes, int n_in,
                              void* d_out, int out_size, void* d_ws, size_t ws_size,
                              hipStream_t stream) {
    const float4* x4   = (const float4*)d_in[0];  // logits fp32 [B,10]
    const int2*   tgt2 = (const int2*)  d_in[1];  // targets int32 [B]
    const int*    ep   = (const int*)   d_in[2];  // epoch scalar
    float* out = (float*)d_out;

    float* partial = (float*)d_ws;            // NBLK floats
    int*   flags   = (int*)d_ws + NBLK;       // NBLK ints  (64 KB total)

    ce_partial_kernel<<<NBLK, 256, 0, stream>>>(x4, tgt2, partial, flags);
    reduce_kernel<<<1, 256, 0, stream>>>(partial, flags, ep, out);
}